// Round 1
// baseline (148.832 us; speedup 1.0000x reference)
//
#include <hip/hip_runtime.h>
#include <hip/hip_bf16.h>

// Problem constants (from reference)
#define BATCH 16
#define HH 1024
#define WW 2048
#define HWPIX (HH * WW)          // 2,097,152 pixels per batch
#define NINST 256                // ids 101..355 -> index 0..254 (pad to 256)

#define BLOCKS_PER_BATCH 128
#define THREADS 256
#define PIX_PER_BLOCK (HWPIX / BLOCKS_PER_BATCH)      // 16384
#define ITERS (PIX_PER_BLOCK / (THREADS * 4))          // 16

typedef unsigned long long u64;

// Packing: bits [0,24) = sum_x, [24,47) = sum_y, [47,..) = count.
// Max per-(batch,id): cnt ~6.2e3 (<2^17), sx ~1.27e7 (<2^24), sy ~6.3e6 (<2^23).
// No cross-field carries possible -> one u64 atomic add per pixel.

__global__ __launch_bounds__(THREADS) void accum_kernel(
    const float* __restrict__ logits, const int* __restrict__ label,
    u64* __restrict__ g_acc, double* __restrict__ g_exp)
{
    __shared__ u64 lds_acc[NINST];
    const int tid   = threadIdx.x;
    const int batch = blockIdx.x >> 7;          // / BLOCKS_PER_BATCH
    const int blk   = blockIdx.x & 127;         // % BLOCKS_PER_BATCH

    lds_acc[tid] = 0ull;
    __syncthreads();

    const float4* lg4 = (const float4*)logits + (size_t)batch * (HWPIX / 4);
    const int4*   lb4 = (const int4*)label   + (size_t)batch * (HWPIX / 4);
    const int gbase = blk * (PIX_PER_BLOCK / 4);

    float es = 0.f;
#pragma unroll
    for (int i = 0; i < ITERS; ++i) {
        const int g = gbase + i * THREADS + tid;     // float4-group index
        const float4 f  = lg4[g];
        const int4   lb = lb4[g];
        es += __expf(f.x) + __expf(f.y) + __expf(f.z) + __expf(f.w);
        const int p0 = g << 2;                       // first pixel of group
        const int y  = p0 >> 11;                     // W = 2048
        const int x0 = p0 & 2047;
        const u64 base = ((u64)1 << 47) | ((u64)y << 24);
        if (lb.x > 100) atomicAdd(&lds_acc[lb.x - 101], base | (u64)(x0 + 0));
        if (lb.y > 100) atomicAdd(&lds_acc[lb.y - 101], base | (u64)(x0 + 1));
        if (lb.z > 100) atomicAdd(&lds_acc[lb.z - 101], base | (u64)(x0 + 2));
        if (lb.w > 100) atomicAdd(&lds_acc[lb.w - 101], base | (u64)(x0 + 3));
    }

    // exp partial: wave64 shuffle reduce, then one f64 atomic per wave
    for (int off = 32; off > 0; off >>= 1) es += __shfl_down(es, off, 64);
    if ((tid & 63) == 0) atomicAdd(g_exp, (double)es);

    __syncthreads();
    const u64 v = lds_acc[tid];
    if (v) atomicAdd(&g_acc[batch * NINST + tid], v);
}

__global__ __launch_bounds__(256) void finalize_kernel(
    const float* __restrict__ logits, const u64* __restrict__ g_acc,
    const double* __restrict__ g_exp, float* __restrict__ out)
{
    const int tid = threadIdx.x;
    float s = 0.f;
    if (tid < 255) {                    // id = 101 + tid
        for (int b = 0; b < BATCH; ++b) {
            const u64 v = g_acc[b * NINST + tid];
            const unsigned cnt = (unsigned)(v >> 47);
            if (cnt) {
                const unsigned sx = (unsigned)(v & 0xFFFFFFu);
                const unsigned sy = (unsigned)((v >> 24) & 0x7FFFFFu);
                const float fc = (float)cnt;
                // identical f32 divide + truncation as the reference
                const int cx = (int)((float)sx / fc);
                const int cy = (int)((float)sy / fc);
                s += logits[(size_t)b * HWPIX + (size_t)cy * WW + cx];
            }
        }
    }
    __shared__ float red[256];
    red[tid] = s;
    __syncthreads();
    for (int off = 128; off > 0; off >>= 1) {
        if (tid < off) red[tid] += red[tid + off];
        __syncthreads();
    }
    if (tid == 0) {
        const double int_loss = *g_exp / (double)((double)BATCH * (double)HWPIX);
        out[0] = (float)(int_loss - (double)red[0] / (double)BATCH);
    }
}

extern "C" void kernel_launch(void* const* d_in, const int* in_sizes, int n_in,
                              void* d_out, int out_size, void* d_ws, size_t ws_size,
                              hipStream_t stream) {
    const float* logits = (const float*)d_in[0];
    const int*   label  = (const int*)d_in[1];
    float* out = (float*)d_out;

    u64*    g_acc = (u64*)d_ws;
    double* g_exp = (double*)((char*)d_ws + (size_t)BATCH * NINST * sizeof(u64));

    // zero accumulators every call (harness does not re-poison between replays)
    hipMemsetAsync(d_ws, 0, (size_t)BATCH * NINST * sizeof(u64) + sizeof(double), stream);

    accum_kernel<<<BATCH * BLOCKS_PER_BATCH, THREADS, 0, stream>>>(logits, label, g_acc, g_exp);
    finalize_kernel<<<1, 256, 0, stream>>>(logits, g_acc, g_exp, out);
}

// Round 2
// 73.569 us; speedup vs baseline: 2.0230x; 2.0230x over previous
//
#include <hip/hip_runtime.h>
#include <hip/hip_bf16.h>

// Problem constants (from reference)
#define BATCH 16
#define HH 1024
#define WW 2048
#define HWPIX (HH * WW)            // 2,097,152 pixels per batch
#define NID 255                    // ids 101..355 -> index 0..254

#define THREADS 1024
#define SLICES 16                  // blocks per batch; 16*16 = 256 blocks = 1/CU
#define PIX_PER_BLOCK (HWPIX / SLICES)        // 131072 (64 rows of 2048)
#define ROWS_PER_BLOCK (PIX_PER_BLOCK / WW)   // 64
#define ITERS (PIX_PER_BLOCK / (THREADS * 4)) // 32

typedef unsigned long long u64;

// Per-lane-column packing (column accumulates <=128 pixels, one thread's work):
//   bits [0,24)  = sum_x      (max 128*2047 = 262,016 < 2^24)
//   bits [24,40) = sum_y_rel  (max 128*63   = 8,064   < 2^16)
//   bits [40,..) = count      (max 128)
// All fields overflow-free by construction -> plain u64 adds, no carries.

__global__ __launch_bounds__(THREADS, 1) void accum_kernel(
    const float* __restrict__ logits, const int* __restrict__ label,
    unsigned* __restrict__ g_cnt, unsigned* __restrict__ g_sx,
    unsigned* __restrict__ g_sy, double* __restrict__ g_exp)
{
    __shared__ u64 table[NID * 64];        // [id][lane] : 130,560 B
    __shared__ double exp_lds[16];

    const int tid  = threadIdx.x;
    const int lane = tid & 63;
    const int batch = blockIdx.x >> 4;
    const int slice = blockIdx.x & 15;

    for (int i = tid; i < NID * 64; i += THREADS) table[i] = 0ull;
    __syncthreads();

    const float4* lg4 = (const float4*)logits + (size_t)batch * (HWPIX / 4) + slice * (PIX_PER_BLOCK / 4);
    const int4*   lb4 = (const int4*)label   + (size_t)batch * (HWPIX / 4) + slice * (PIX_PER_BLOCK / 4);

    float es = 0.f;
#pragma unroll 4
    for (int i = 0; i < ITERS; ++i) {
        const int g = i * THREADS + tid;          // float4-group within slice
        const float4 f  = lg4[g];
        const int4   lb = lb4[g];
        es += __expf(f.x) + __expf(f.y) + __expf(f.z) + __expf(f.w);
        const int p0 = g << 2;                    // pixel index within slice
        const int yr = p0 >> 11;                  // row within slice (0..63)
        const int x0 = p0 & 2047;
        const u64 base = ((u64)1 << 40) | ((u64)yr << 24);
        if (lb.x > 100) atomicAdd(&table[(lb.x - 101) * 64 + lane], base | (u64)(x0 + 0));
        if (lb.y > 100) atomicAdd(&table[(lb.y - 101) * 64 + lane], base | (u64)(x0 + 1));
        if (lb.z > 100) atomicAdd(&table[(lb.z - 101) * 64 + lane], base | (u64)(x0 + 2));
        if (lb.w > 100) atomicAdd(&table[(lb.w - 101) * 64 + lane], base | (u64)(x0 + 3));
    }

    // exp partial: wave shuffle reduce -> LDS -> ONE f64 atomic per block
    for (int off = 32; off > 0; off >>= 1) es += __shfl_down(es, off, 64);
    if (lane == 0) exp_lds[tid >> 6] = (double)es;
    __syncthreads();
    if (tid == 0) {
        double t = 0.0;
        for (int w = 0; w < 16; ++w) t += exp_lds[w];
        atomicAdd(g_exp, t);
    }

    // flush: thread id (<255) sums its id's 64 lane-columns, 3 u32 atomics out
    if (tid < NID) {
        unsigned cnt = 0, sx = 0, syr = 0;
        const u64* col = &table[tid * 64];
        for (int l = 0; l < 64; ++l) {
            const u64 v = col[l];
            cnt += (unsigned)(v >> 40);
            syr += (unsigned)((v >> 24) & 0xFFFFu);
            sx  += (unsigned)(v & 0xFFFFFFu);
        }
        if (cnt) {
            const unsigned base_row = slice * ROWS_PER_BLOCK;
            atomicAdd(&g_cnt[batch * NID + tid], cnt);
            atomicAdd(&g_sx [batch * NID + tid], sx);
            atomicAdd(&g_sy [batch * NID + tid], syr + base_row * cnt);
        }
    }
}

__global__ __launch_bounds__(256) void finalize_kernel(
    const float* __restrict__ logits, const unsigned* __restrict__ g_cnt,
    const unsigned* __restrict__ g_sx, const unsigned* __restrict__ g_sy,
    const double* __restrict__ g_exp, float* __restrict__ out)
{
    const int tid = threadIdx.x;
    float s = 0.f;
    if (tid < NID) {                    // id = 101 + tid
        for (int b = 0; b < BATCH; ++b) {
            const unsigned cnt = g_cnt[b * NID + tid];
            if (cnt) {
                const float fc = (float)cnt;
                // identical f32 divide + truncation as the reference
                const int cx = (int)((float)g_sx[b * NID + tid] / fc);
                const int cy = (int)((float)g_sy[b * NID + tid] / fc);
                s += logits[(size_t)b * HWPIX + (size_t)cy * WW + cx];
            }
        }
    }
    __shared__ float red[256];
    red[tid] = s;
    __syncthreads();
    for (int off = 128; off > 0; off >>= 1) {
        if (tid < off) red[tid] += red[tid + off];
        __syncthreads();
    }
    if (tid == 0) {
        const double int_loss = *g_exp / (double)((double)BATCH * (double)HWPIX);
        out[0] = (float)(int_loss - (double)red[0] / (double)BATCH);
    }
}

extern "C" void kernel_launch(void* const* d_in, const int* in_sizes, int n_in,
                              void* d_out, int out_size, void* d_ws, size_t ws_size,
                              hipStream_t stream) {
    const float* logits = (const float*)d_in[0];
    const int*   label  = (const int*)d_in[1];
    float* out = (float*)d_out;

    unsigned* g_cnt = (unsigned*)d_ws;
    unsigned* g_sx  = g_cnt + BATCH * NID;
    unsigned* g_sy  = g_sx  + BATCH * NID;
    double*   g_exp = (double*)(g_sy + BATCH * NID);   // 48,960 B offset, 8-aligned

    // zero accumulators every call (harness does not re-poison between replays)
    hipMemsetAsync(d_ws, 0, (size_t)BATCH * NID * 3 * sizeof(unsigned) + sizeof(double), stream);

    accum_kernel<<<BATCH * SLICES, THREADS, 0, stream>>>(logits, label, g_cnt, g_sx, g_sy, g_exp);
    finalize_kernel<<<1, 256, 0, stream>>>(logits, g_cnt, g_sx, g_sy, g_exp, out);
}